// Round 18
// baseline (529.877 us; speedup 1.0000x reference)
//
#include <hip/hip_runtime.h>
#include <hip/hip_bf16.h>

constexpr int V   = 100000;
constexpr int E   = 1600000;
constexpr int NET = 10;
constexpr int KXW = 138;              // W_xi row length (2*64+10)
constexpr int NB  = (V + 255) / 256;  // 391 blocks over nodes
constexpr int GN  = 8;                // partial-CSR groups (≈ XCDs)
constexpr int GV  = GN * V;           // 800000
constexpr int NBG = (GV + 255) / 256; // 3125
constexpr float MUS   = 0.1125f;      // MU / S
constexpr float SP    = 0.025f;       // int8 P scale
constexpr float LOG2E = 1.44269504f;
constexpr float S2L   = 2.0f * SP * LOG2E;   // int8 P step in exp2 domain
constexpr float AS    = MUS / 127.0f;        // int8 A decode scale

typedef __attribute__((ext_vector_type(8))) short short8;
typedef __attribute__((ext_vector_type(4))) float float4v;

__device__ __forceinline__ float fast_tanh(float x) {
    return 1.0f - 2.0f * __builtin_amdgcn_rcpf(__expf(2.0f * x) + 1.0f);
}
__device__ __forceinline__ float bflo(unsigned u) { return __uint_as_float(u << 16); }
__device__ __forceinline__ float bfhi(unsigned u) { return __uint_as_float(u & 0xffff0000u); }
__device__ __forceinline__ short f2bf(float x) {
    union { __hip_bfloat16 b; short s; } u; u.b = __float2bfloat16(x); return u.s;
}

__device__ __forceinline__ float ub0(unsigned u) {
#if __has_builtin(__builtin_amdgcn_cvt_f32_ubyte0)
    return __builtin_amdgcn_cvt_f32_ubyte0(u);
#else
    return (float)(u & 0xff);
#endif
}
__device__ __forceinline__ float ub1(unsigned u) {
#if __has_builtin(__builtin_amdgcn_cvt_f32_ubyte1)
    return __builtin_amdgcn_cvt_f32_ubyte1(u);
#else
    return (float)((u >> 8) & 0xff);
#endif
}
__device__ __forceinline__ float ub2(unsigned u) {
#if __has_builtin(__builtin_amdgcn_cvt_f32_ubyte2)
    return __builtin_amdgcn_cvt_f32_ubyte2(u);
#else
    return (float)((u >> 16) & 0xff);
#endif
}
__device__ __forceinline__ float ub3(unsigned u) {
#if __has_builtin(__builtin_amdgcn_cvt_f32_ubyte3)
    return __builtin_amdgcn_cvt_f32_ubyte3(u);
#else
    return (float)(u >> 24);
#endif
}
__device__ __forceinline__ unsigned pku8(float f, unsigned pos, unsigned old) {
#if __has_builtin(__builtin_amdgcn_cvt_pk_u8_f32)
    return __builtin_amdgcn_cvt_pk_u8_f32(f, pos, old);
#else
    return old | ((unsigned)f << (8 * pos));
#endif
}

// ---------------------------------------------------------------------------
// 8-way histogram: countg[g][v], g = blockIdx&7 (same grid as scatterg).
// ---------------------------------------------------------------------------
__global__ __launch_bounds__(256) void histg_kernel(
    const int* __restrict__ xneis, int* __restrict__ countg)
{
    int e = blockIdx.x * 256 + threadIdx.x;
    if (e >= E) return;
    int g = blockIdx.x & (GN - 1);
    int nr = xneis[e];
    if (nr < V) atomicAdd(&countg[g * V + nr], 1);
}

// Fused: cnt_tot[v] = sum_g countg[g][v]; blockwise-exclusive scan of cnt_tot.
__global__ __launch_bounds__(256) void scanV_kernel(
    const int* __restrict__ countg, int* __restrict__ cnt_tot,
    int* __restrict__ scanned, int* __restrict__ bsum)
{
    __shared__ int s[256];
    int tid = threadIdx.x;
    int i = blockIdx.x * 256 + tid;
    int c = 0;
    if (i < V) {
        #pragma unroll
        for (int g = 0; g < GN; ++g) c += countg[g * V + i];
        cnt_tot[i] = c;
    }
    s[tid] = c; __syncthreads();
    #pragma unroll
    for (int off = 1; off < 256; off <<= 1) {
        int t = (tid >= off) ? s[tid - off] : 0;
        __syncthreads();
        s[tid] += t;
        __syncthreads();
    }
    if (i < V) scanned[i] = s[tid] - c;
    if (tid == 255) bsum[blockIdx.x] = s[255];
}

// Generic block-exclusive scan (used for the GV level-0 scan).
__global__ __launch_bounds__(256) void scan_block_kernel(
    const int* __restrict__ in, int* __restrict__ out, int* __restrict__ bsum, int n)
{
    __shared__ int s[256];
    int tid = threadIdx.x;
    int i = blockIdx.x * 256 + tid;
    int v = (i < n) ? in[i] : 0;
    s[tid] = v; __syncthreads();
    #pragma unroll
    for (int off = 1; off < 256; off <<= 1) {
        int t = (tid >= off) ? s[tid - off] : 0;
        __syncthreads();
        s[tid] += t;
        __syncthreads();
    }
    if (i < n) out[i] = s[tid] - v;
    if (tid == 255) bsum[blockIdx.x] = s[255];
}

// Single-block full exclusive scan with running carry.
__global__ __launch_bounds__(256) void scan_mid_kernel(
    const int* __restrict__ in, int* __restrict__ out, int n)
{
    __shared__ int s[256];
    __shared__ int carry;
    int tid = threadIdx.x;
    if (tid == 0) carry = 0;
    __syncthreads();
    for (int base = 0; base < n; base += 256) {
        int i = base + tid;
        int x = (i < n) ? in[i] : 0;
        s[tid] = x; __syncthreads();
        #pragma unroll
        for (int off = 1; off < 256; off <<= 1) {
            int t = (tid >= off) ? s[tid - off] : 0;
            __syncthreads();
            s[tid] += t;
            __syncthreads();
        }
        int incl = s[tid];
        int c = carry;
        if (i < n) out[i] = c + incl - x;
        __syncthreads();
        if (tid == 255) carry = c + incl;
        __syncthreads();
    }
}

__global__ __launch_bounds__(256) void add_gen_kernel(
    int* __restrict__ arr, const int* __restrict__ tops, int n)
{
    int i = blockIdx.x * 256 + threadIdx.x;
    if (i < n) arr[i] += tops[i >> 8];
}

// rowptr path (V entries + total), NB <= 512
__global__ __launch_bounds__(512) void scan_tops_kernel(
    const int* __restrict__ blocksum, int* __restrict__ tops, int* __restrict__ rowptr)
{
    __shared__ int s[512];
    int tid = threadIdx.x;
    int v = (tid < NB) ? blocksum[tid] : 0;
    s[tid] = v; __syncthreads();
    #pragma unroll
    for (int off = 1; off < 512; off <<= 1) {
        int t = (tid >= off) ? s[tid - off] : 0;
        __syncthreads();
        s[tid] += t;
        __syncthreads();
    }
    if (tid < NB) tops[tid] = s[tid] - v;        // exclusive
    if (tid == 511) rowptr[V] = s[511];          // total kept edges
}

__global__ __launch_bounds__(256) void add_offsets_kernel(
    const int* __restrict__ scanned, const int* __restrict__ tops, int* __restrict__ rowptr)
{
    int i = blockIdx.x * 256 + threadIdx.x;
    if (i < V) rowptr[i] = scanned[i] + tops[blockIdx.x];
}

// Scatter into group-g partial CSR (g = blockIdx&7, same grid as histg).
// meta word: src (17 b) | et (4 b) | dg-1 (6 b)
__global__ __launch_bounds__(256) void scatterg_kernel(
    const int* __restrict__ xnode, const int* __restrict__ xneis,
    const int* __restrict__ etype, const float* __restrict__ dg,
    const int* __restrict__ rpg, int* __restrict__ cursorg,
    unsigned* __restrict__ pmeta)
{
    int e = blockIdx.x * 256 + threadIdx.x;
    if (e >= E) return;
    int g = blockIdx.x & (GN - 1);
    int nr = xneis[e];
    if (nr < V) {
        int idx = g * V + nr;
        int p = rpg[idx] + atomicAdd(&cursorg[idx], 1);
        unsigned src = (unsigned)(xnode[e] - 1);
        unsigned et  = (unsigned)(etype[e] - 1);
        unsigned dgi = (unsigned)dg[e] - 1;        // 0..63, exact
        pmeta[p] = src | (et << 17) | (dgi << 21);
    }
}

// ---------------------------------------------------------------------------
// Per-node bias sum + bf16 H_init.
// ---------------------------------------------------------------------------
__global__ __launch_bounds__(256) void bsum_kernel(
    const float* __restrict__ feat, const int* __restrict__ count,
    const float* __restrict__ Wrou, const float* __restrict__ brou,
    const float* __restrict__ Hinit, float* __restrict__ Bsum,
    ushort* __restrict__ Hb0)
{
    __shared__ float Wl[512];
    __shared__ float bl[8];
    int tid = threadIdx.x;
    for (int i = tid; i < 512; i += 256) Wl[i] = Wrou[i];
    if (tid < 8) bl[tid] = brou[tid];
    __syncthreads();

    int v = blockIdx.x * 256 + tid;
    if (v >= V) return;
    int c = count[v];
    float out[8] = {0, 0, 0, 0, 0, 0, 0, 0};
    if (c > 0) {                                  // c>0 implies v >= 1
        const float4* f4 = (const float4*)(feat + (size_t)(v - 1) * 64);
        float acc[8];
        #pragma unroll
        for (int s = 0; s < 8; ++s) acc[s] = bl[s];
        #pragma unroll 4
        for (int k = 0; k < 16; ++k) {
            float4 x = f4[k];
            #pragma unroll
            for (int s = 0; s < 8; ++s) {
                const float* w = &Wl[s * 64 + k * 4];
                acc[s] += x.x * w[0] + x.y * w[1] + x.z * w[2] + x.w * w[3];
            }
        }
        float fc = (float)c;
        #pragma unroll
        for (int s = 0; s < 8; ++s) out[s] = fc * fast_tanh(acc[s]);
    }
    float4* O = (float4*)(Bsum + (size_t)v * 8);
    O[0] = make_float4(out[0], out[1], out[2], out[3]);
    O[1] = make_float4(out[4], out[5], out[6], out[7]);

    const float* Hh = Hinit + (size_t)v * 8;
    uint4 pk;
    pk.x = (unsigned)(ushort)f2bf(Hh[0]) | ((unsigned)(ushort)f2bf(Hh[1]) << 16);
    pk.y = (unsigned)(ushort)f2bf(Hh[2]) | ((unsigned)(ushort)f2bf(Hh[3]) << 16);
    pk.z = (unsigned)(ushort)f2bf(Hh[4]) | ((unsigned)(ushort)f2bf(Hh[5]) << 16);
    pk.w = (unsigned)(ushort)f2bf(Hh[6]) | ((unsigned)(ushort)f2bf(Hh[7]) << 16);
    *(uint4*)(Hb0 + (size_t)v * 8) = pk;
}

// ---------------------------------------------------------------------------
// PQ GEMM (MFMA): P[v] -> int8 biased (6.4 MB), Q[v] -> bf16 (12.8 MB)
// ---------------------------------------------------------------------------
__global__ __launch_bounds__(256) void pq_kernel(
    const float* __restrict__ feat, const float* __restrict__ Wxi,
    unsigned char* __restrict__ P8, ushort* __restrict__ Qb)
{
    const int lane = threadIdx.x & 63, wave = threadIdx.x >> 6;
    const int quad = lane >> 4, l16 = lane & 15;

    short8 bP[4][2], bQ[4][2];
    #pragma unroll
    for (int nt = 0; nt < 4; ++nt) {
        #pragma unroll
        for (int ks = 0; ks < 2; ++ks) {
            const float* wp = Wxi + (size_t)(nt * 16 + l16) * KXW + ks * 32 + quad * 8;
            short8 p, q;
            #pragma unroll
            for (int j = 0; j < 8; ++j) { p[j] = f2bf(wp[j]); q[j] = f2bf(wp[64 + j]); }
            bP[nt][ks] = p; bQ[nt][ks] = q;
        }
    }

    int t = blockIdx.x * 4 + wave;
    if (t >= V / 16) return;
    int v0 = t * 16;

    const float* fp = feat + (size_t)(v0 + l16) * 64 + quad * 8;
    short8 a0, a1;
    #pragma unroll
    for (int j = 0; j < 8; ++j) { a0[j] = f2bf(fp[j]); a1[j] = f2bf(fp[32 + j]); }

    float4v accP[4], accQ[4];
    #pragma unroll
    for (int nt = 0; nt < 4; ++nt) {
        float4v z = {0.f, 0.f, 0.f, 0.f};
        z = __builtin_amdgcn_mfma_f32_16x16x32_bf16(a0, bP[nt][0], z, 0, 0, 0);
        z = __builtin_amdgcn_mfma_f32_16x16x32_bf16(a1, bP[nt][1], z, 0, 0, 0);
        accP[nt] = z;
        float4v w = {0.f, 0.f, 0.f, 0.f};
        w = __builtin_amdgcn_mfma_f32_16x16x32_bf16(a0, bQ[nt][0], w, 0, 0, 0);
        w = __builtin_amdgcn_mfma_f32_16x16x32_bf16(a1, bQ[nt][1], w, 0, 0, 0);
        accQ[nt] = w;
    }

    #pragma unroll
    for (int r = 0; r < 4; ++r) {
        int row = v0 + quad * 4 + r;
        #pragma unroll
        for (int nt = 0; nt < 4; ++nt) {
            int col = nt * 16 + l16;
            int q8 = (int)rintf(accP[nt][r] * (1.0f / SP)) + 128;
            q8 = min(max(q8, 0), 255);
            P8[row * 64 + col] = (unsigned char)q8;
            Qb[row * 64 + col] = (ushort)f2bf(accQ[nt][r]);
        }
    }
}

// ---------------------------------------------------------------------------
// A materialization, TWO-PHASE per 64-edge batch (r17: all 8 s-lanes of an
// edge duplicated the segment-select chain + meta decode — 8x wasted VALU,
// the bulk of amat's 82% VALUBusy). Phase 1: one lane per edge resolves the
// segment + loads pmeta + writes esrc. Phase 2: __shfl broadcasts the meta
// word to the 8 s-lanes. Plain (cacheable) A8 stores — NT was neutral on
// FETCH and blocks A8's L3 residency for the steps.
// ---------------------------------------------------------------------------
__global__ __launch_bounds__(256) void amat_kernel(
    const unsigned* __restrict__ pmeta, const int* __restrict__ countg,
    const int* __restrict__ rpg, const int* __restrict__ rowptr,
    const unsigned char* __restrict__ P8, const ushort* __restrict__ Qb,
    const float* __restrict__ Wxi, const float* __restrict__ bxi,
    unsigned char* __restrict__ A8, int* __restrict__ esrc)
{
    __shared__ float Wet2[NET * 64];     // 2*log2e*(Wxi[n][128+et]+bxi[n])
    __shared__ float scT[64];            // 127/dg
    int tid = threadIdx.x;
    for (int i = tid; i < NET * 64; i += 256) {
        int et = i >> 6, n = i & 63;
        Wet2[i] = 2.0f * LOG2E * (Wxi[n * KXW + 128 + et] + bxi[n]);
    }
    if (tid < 64) scT[tid] = 127.0f / (float)(tid + 1);
    __syncthreads();

    int v = blockIdx.x * 4 + (tid >> 6);
    if (v >= V) return;
    int lane = tid & 63;
    int el = lane >> 3, s = lane & 7;

    // 8-segment table (count, base) -> prefix
    int cg = 0, bg = 0;
    if (lane < 8) { cg = countg[lane * V + v]; bg = rpg[lane * V + v]; }
    int prefA[8], baseA[8];
    int pref = 0;
    #pragma unroll
    for (int g = 0; g < GN; ++g) {
        prefA[g] = pref;
        baseA[g] = __shfl(bg, g);
        pref += __shfl(cg, g);
    }
    const int deg = pref;
    const int off = rowptr[v];

    float q0, q1, q2, q3, q4, q5, q6, q7;
    {
        uint4 qu = *(const uint4*)(Qb + v * 64 + s * 8);
        const float B = 128.0f * SP, C = 2.0f * LOG2E;
        q0 = C * (bflo(qu.x) - B); q1 = C * (bfhi(qu.x) - B);
        q2 = C * (bflo(qu.y) - B); q3 = C * (bfhi(qu.y) - B);
        q4 = C * (bflo(qu.z) - B); q5 = C * (bfhi(qu.z) - B);
        q6 = C * (bflo(qu.w) - B); q7 = C * (bfhi(qu.w) - B);
    }

    for (int base = 0; base < deg; base += 64) {
        // phase 1: this lane resolves edge (base+lane)
        unsigned m_mine = 0;
        {
            int i1 = base + lane;
            if (i1 < deg) {
                int gg = 0;
                #pragma unroll
                for (int g = 1; g < GN; ++g) if (i1 >= prefA[g]) gg = g;
                int p = baseA[gg] + (i1 - prefA[gg]);
                m_mine = pmeta[p];
                esrc[off + i1] = (int)(m_mine & 0x1FFFF);
            }
        }
        // phase 2: 8 edges per sub-round, meta via shfl broadcast
        int nb = deg - base;                      // >0
        for (int k = 0; k * 8 + el < nb && k < 8; ++k) {
            int ib = k * 8 + el;
            int i = base + ib;
            unsigned m = __shfl(m_mine, ib);
            int src = (int)(m & 0x1FFFF);
            int et  = (int)((m >> 17) & 0xF);
            float kk  = scT[m >> 21];
            float m2k = -2.0f * kk;
            float ck  = kk + 128.5f;

            uint2 pu = *(const uint2*)(P8 + src * 64 + s * 8);
            const float4* w4 = (const float4*)(&Wet2[et * 64 + s * 8]);
            float4 wa = w4[0], wb = w4[1];

            float r0 = __builtin_amdgcn_rcpf(__builtin_amdgcn_exp2f(fmaf(ub0(pu.x), S2L, q0 + wa.x)) + 1.0f);
            float r1 = __builtin_amdgcn_rcpf(__builtin_amdgcn_exp2f(fmaf(ub1(pu.x), S2L, q1 + wa.y)) + 1.0f);
            float r2 = __builtin_amdgcn_rcpf(__builtin_amdgcn_exp2f(fmaf(ub2(pu.x), S2L, q2 + wa.z)) + 1.0f);
            float r3 = __builtin_amdgcn_rcpf(__builtin_amdgcn_exp2f(fmaf(ub3(pu.x), S2L, q3 + wa.w)) + 1.0f);
            float r4 = __builtin_amdgcn_rcpf(__builtin_amdgcn_exp2f(fmaf(ub0(pu.y), S2L, q4 + wb.x)) + 1.0f);
            float r5 = __builtin_amdgcn_rcpf(__builtin_amdgcn_exp2f(fmaf(ub1(pu.y), S2L, q5 + wb.y)) + 1.0f);
            float r6 = __builtin_amdgcn_rcpf(__builtin_amdgcn_exp2f(fmaf(ub2(pu.y), S2L, q6 + wb.z)) + 1.0f);
            float r7 = __builtin_amdgcn_rcpf(__builtin_amdgcn_exp2f(fmaf(ub3(pu.y), S2L, q7 + wb.w)) + 1.0f);

            uint2 o;
            o.x = pku8(fmaf(r3, m2k, ck), 3,
                  pku8(fmaf(r2, m2k, ck), 2,
                  pku8(fmaf(r1, m2k, ck), 1,
                  pku8(fmaf(r0, m2k, ck), 0, 0u))));
            o.y = pku8(fmaf(r7, m2k, ck), 3,
                  pku8(fmaf(r6, m2k, ck), 2,
                  pku8(fmaf(r5, m2k, ck), 1,
                  pku8(fmaf(r4, m2k, ck), 0, 0u))));
            *(uint2*)(A8 + (unsigned)(off + i) * 64u + (unsigned)(s * 8)) = o;
        }
    }
}

// ---------------------------------------------------------------------------
// Light step, 2x-unrolled (32 edges in flight per wave), bf16 H gathers,
// csum computed in-loop.
// ---------------------------------------------------------------------------
__global__ __launch_bounds__(256) void step_kernel(
    const ushort* __restrict__ HbIn, ushort* __restrict__ HbOut,
    const int* __restrict__ esrc, const int* __restrict__ rowptr,
    const unsigned char* __restrict__ A8, const float* __restrict__ Bsum,
    const float* __restrict__ W1, const float* __restrict__ b1,
    float* __restrict__ logitsOut, float* __restrict__ HfpOut)
{
    int v = blockIdx.x * 4 + (threadIdx.x >> 6);
    if (v >= V) return;
    int lane = threadIdx.x & 63;
    int el = lane >> 2, q = lane & 3;

    int p0 = rowptr[v], p1 = rowptr[v + 1];

    float accE = 0.0f, accO = 0.0f, csum = 0.0f;
    int p = p0 + el;
    for (; p + 16 < p1; p += 32) {
        int srcA = esrc[p], srcB = esrc[p + 16];
        uint4 auA = *(const uint4*)(A8 + (unsigned)p * 64u + (unsigned)(q * 16));
        uint4 auB = *(const uint4*)(A8 + (unsigned)(p + 16) * 64u + (unsigned)(q * 16));
        uint4 hbA = *(const uint4*)(HbIn + srcA * 8);
        uint4 hbB = *(const uint4*)(HbIn + srcB * 8);

        float a0x = bflo(hbA.x), a0y = bfhi(hbA.x), a0z = bflo(hbA.y), a0w = bfhi(hbA.y);
        float a1x = bflo(hbA.z), a1y = bfhi(hbA.z), a1z = bflo(hbA.w), a1w = bfhi(hbA.w);
        csum += ((a0x + a0y) + (a0z + a0w)) + ((a1x + a1y) + (a1z + a1w));
        accE += ub0(auA.x) * a0x + ub1(auA.x) * a0y + ub2(auA.x) * a0z + ub3(auA.x) * a0w
              + ub0(auA.y) * a1x + ub1(auA.y) * a1y + ub2(auA.y) * a1z + ub3(auA.y) * a1w;
        accO += ub0(auA.z) * a0x + ub1(auA.z) * a0y + ub2(auA.z) * a0z + ub3(auA.z) * a0w
              + ub0(auA.w) * a1x + ub1(auA.w) * a1y + ub2(auA.w) * a1z + ub3(auA.w) * a1w;

        float b0x = bflo(hbB.x), b0y = bfhi(hbB.x), b0z = bflo(hbB.y), b0w = bfhi(hbB.y);
        float b1x = bflo(hbB.z), b1y = bfhi(hbB.z), b1z = bflo(hbB.w), b1w = bfhi(hbB.w);
        csum += ((b0x + b0y) + (b0z + b0w)) + ((b1x + b1y) + (b1z + b1w));
        accE += ub0(auB.x) * b0x + ub1(auB.x) * b0y + ub2(auB.x) * b0z + ub3(auB.x) * b0w
              + ub0(auB.y) * b1x + ub1(auB.y) * b1y + ub2(auB.y) * b1z + ub3(auB.y) * b1w;
        accO += ub0(auB.z) * b0x + ub1(auB.z) * b0y + ub2(auB.z) * b0z + ub3(auB.z) * b0w
              + ub0(auB.w) * b1x + ub1(auB.w) * b1y + ub2(auB.w) * b1z + ub3(auB.w) * b1w;
    }
    if (p < p1) {
        int src = esrc[p];
        uint4 au = *(const uint4*)(A8 + (unsigned)p * 64u + (unsigned)(q * 16));
        uint4 hb = *(const uint4*)(HbIn + src * 8);
        float h0x = bflo(hb.x), h0y = bfhi(hb.x), h0z = bflo(hb.y), h0w = bfhi(hb.y);
        float h1x = bflo(hb.z), h1y = bfhi(hb.z), h1z = bflo(hb.w), h1w = bfhi(hb.w);
        csum += ((h0x + h0y) + (h0z + h0w)) + ((h1x + h1y) + (h1z + h1w));
        accE += ub0(au.x) * h0x + ub1(au.x) * h0y + ub2(au.x) * h0z + ub3(au.x) * h0w
              + ub0(au.y) * h1x + ub1(au.y) * h1y + ub2(au.y) * h1z + ub3(au.y) * h1w;
        accO += ub0(au.z) * h0x + ub1(au.z) * h0y + ub2(au.z) * h0z + ub3(au.z) * h0w
              + ub0(au.w) * h1x + ub1(au.w) * h1y + ub2(au.w) * h1z + ub3(au.w) * h1w;
    }
    accE += __shfl_xor(accE, 4);  accE += __shfl_xor(accE, 8);
    accE += __shfl_xor(accE, 16); accE += __shfl_xor(accE, 32);
    accO += __shfl_xor(accO, 4);  accO += __shfl_xor(accO, 8);
    accO += __shfl_xor(accO, 16); accO += __shfl_xor(accO, 32);
    csum += __shfl_xor(csum, 4);  csum += __shfl_xor(csum, 8);
    csum += __shfl_xor(csum, 16); csum += __shfl_xor(csum, 32);

    float hE = (accE - 128.0f * csum) * AS + Bsum[v * 8 + q * 2];
    float hO = (accO - 128.0f * csum) * AS + Bsum[v * 8 + q * 2 + 1];

    unsigned pk = (unsigned)(ushort)f2bf(hE) | ((unsigned)(ushort)f2bf(hO) << 16);
    if (el == 0) {
        *(unsigned*)(HbOut + v * 8 + q * 2) = pk;
        if (HfpOut != nullptr)
            *(float2*)(HfpOut + v * 8 + q * 2) = make_float2(hE, hO);
    }
    if (logitsOut != nullptr) {
        float t = hE * W1[q * 2] + hO * W1[q * 2 + 1];
        t += __shfl_xor(t, 1); t += __shfl_xor(t, 2);
        if (lane == 0) logitsOut[v] = t + b1[0];
    }
}

// ---------------------------------------------------------------------------
// Epilogue
// ---------------------------------------------------------------------------
__global__ __launch_bounds__(256) void reduce_max_kernel(
    const float* __restrict__ logits, float* __restrict__ partial)
{
    float m = -INFINITY;
    for (int v = blockIdx.x * 256 + threadIdx.x; v < V; v += 256 * 256)
        m = fmaxf(m, logits[v]);
    #pragma unroll
    for (int o = 32; o > 0; o >>= 1) m = fmaxf(m, __shfl_down(m, o));
    __shared__ float sm[4];
    if ((threadIdx.x & 63) == 0) sm[threadIdx.x >> 6] = m;
    __syncthreads();
    if (threadIdx.x == 0)
        partial[blockIdx.x] = fmaxf(fmaxf(sm[0], sm[1]), fmaxf(sm[2], sm[3]));
}

__global__ __launch_bounds__(256) void final_max_kernel(
    const float* __restrict__ partial, float* __restrict__ M)
{
    float m = partial[threadIdx.x];
    #pragma unroll
    for (int o = 32; o > 0; o >>= 1) m = fmaxf(m, __shfl_down(m, o));
    __shared__ float sm[4];
    if ((threadIdx.x & 63) == 0) sm[threadIdx.x >> 6] = m;
    __syncthreads();
    if (threadIdx.x == 0) *M = fmaxf(fmaxf(sm[0], sm[1]), fmaxf(sm[2], sm[3]));
}

// Stage 1: 64 blocks write per-block partials (9 floats each) — no atomics.
__global__ __launch_bounds__(256) void sum_kernel(
    const float* __restrict__ H, const float* __restrict__ logits,
    const float* __restrict__ Mp, float* __restrict__ partial)
{
    const float M = *Mp;
    float se = 0.0f;
    float sh[8] = {0, 0, 0, 0, 0, 0, 0, 0};
    for (int v = blockIdx.x * 256 + threadIdx.x; v < V; v += 64 * 256) {
        float w = __expf(logits[v] - M);
        se += w;
        const float4* H4 = (const float4*)(H + (size_t)v * 8);
        float4 h0 = H4[0], h1 = H4[1];
        sh[0] += w * h0.x; sh[1] += w * h0.y; sh[2] += w * h0.z; sh[3] += w * h0.w;
        sh[4] += w * h1.x; sh[5] += w * h1.y; sh[6] += w * h1.z; sh[7] += w * h1.w;
    }
    #pragma unroll
    for (int o = 32; o > 0; o >>= 1) {
        se += __shfl_xor(se, o);
        #pragma unroll
        for (int i = 0; i < 8; ++i) sh[i] += __shfl_xor(sh[i], o);
    }
    __shared__ float sm[4][9];
    int wv = threadIdx.x >> 6;
    if ((threadIdx.x & 63) == 0) {
        sm[wv][8] = se;
        #pragma unroll
        for (int i = 0; i < 8; ++i) sm[wv][i] = sh[i];
    }
    __syncthreads();
    if (threadIdx.x == 0) {
        #pragma unroll
        for (int i = 0; i < 9; ++i)
            partial[blockIdx.x * 12 + i] = sm[0][i] + sm[1][i] + sm[2][i] + sm[3][i];
    }
}

__global__ void final_kernel(const float* __restrict__ partial, float* __restrict__ out)
{
    int lane = threadIdx.x;               // 64 threads
    float vals[9];
    #pragma unroll
    for (int i = 0; i < 9; ++i) vals[i] = partial[lane * 12 + i];
    #pragma unroll
    for (int o = 1; o < 64; o <<= 1) {
        #pragma unroll
        for (int i = 0; i < 9; ++i) vals[i] += __shfl_xor(vals[i], o);
    }
    __shared__ float res[9];
    if (lane == 0) {
        #pragma unroll
        for (int i = 0; i < 9; ++i) res[i] = vals[i];
    }
    __syncthreads();
    if (lane < 8) out[lane] = tanhf(res[lane] / res[8]);
}

// ---------------------------------------------------------------------------
extern "C" void kernel_launch(void* const* d_in, const int* in_sizes, int n_in,
                              void* d_out, int out_size, void* d_ws, size_t ws_size,
                              hipStream_t stream)
{
    const float* feat  = (const float*)d_in[0];
    const int*   xnode = (const int*)d_in[1];
    const int*   xneis = (const int*)d_in[2];
    const int*   etype = (const int*)d_in[3];
    const float* dg    = (const float*)d_in[4];
    const float* Hinit = (const float*)d_in[5];
    const float* Wxi   = (const float*)d_in[6];
    const float* bxi   = (const float*)d_in[7];
    const float* Wrou  = (const float*)d_in[8];
    const float* brou  = (const float*)d_in[9];
    const float* W1    = (const float*)d_in[10];
    const float* b1    = (const float*)d_in[11];

    char* ws = (char*)d_ws;
    auto alloc = [&](size_t bytes) -> char* {
        char* p = ws; ws += (bytes + 255) & ~(size_t)255; return p;
    };
    // Budget: ~158 MB total (fits 256 MiB ws)
    unsigned char* A8 = (unsigned char*)alloc((size_t)E * 64); // 102.4 MB int8 A
    unsigned char* P8 = (unsigned char*)alloc((size_t)V * 64); // 6.4 MB int8 P
    ushort*   Qb      = (ushort*)alloc((size_t)V * 64 * 2);    // 12.8 MB bf16 Q
    unsigned* pmeta   = (unsigned*)alloc((size_t)E * 4);       // 6.4 MB partial CSR
    int*      esrc    = (int*)alloc((size_t)E * 4);            // 6.4 MB node-major src
    int*      countg  = (int*)alloc((size_t)2 * GV * 4);       // countg + cursorg
    int*      cursorg = countg + GV;
    int*      rpg     = (int*)alloc((size_t)GV * 4);           // 3.2 MB
    int*      cnt_tot = (int*)alloc((size_t)V * 4);
    int*      scannedT= (int*)alloc((size_t)V * 4);
    int*      rowptr  = (int*)alloc((size_t)(V + 1) * 4);
    int*      bsumT   = (int*)alloc(512 * 4);
    int*      topsT   = (int*)alloc(512 * 4);
    int*      bsumA   = (int*)alloc((size_t)NBG * 4);
    int*      sA      = (int*)alloc((size_t)NBG * 4);
    ushort*   Hb0     = (ushort*)alloc((size_t)V * 8 * 2);     // 1.6 MB bf16 H
    ushort*   HbA     = (ushort*)alloc((size_t)V * 8 * 2);
    ushort*   HbB     = (ushort*)alloc((size_t)V * 8 * 2);
    float*    Hfp     = (float*)alloc((size_t)V * 8 * 4);      // fp32 H (last step)
    float*    Bsum    = (float*)alloc((size_t)V * 8 * 4);
    float*    logits  = (float*)alloc((size_t)V * 4);
    float*    pmax    = (float*)alloc(256 * 4);
    float*    Mp      = (float*)alloc(16);
    float*    spart   = (float*)alloc(64 * 12 * 4);

    hipMemsetAsync(countg, 0, (size_t)2 * GV * 4, stream);
    histg_kernel<<<(E + 255) / 256, 256, 0, stream>>>(xneis, countg);
    scanV_kernel<<<NB, 256, 0, stream>>>(countg, cnt_tot, scannedT, bsumT);
    scan_tops_kernel<<<1, 512, 0, stream>>>(bsumT, topsT, rowptr);
    add_offsets_kernel<<<NB, 256, 0, stream>>>(scannedT, topsT, rowptr);
    scan_block_kernel<<<NBG, 256, 0, stream>>>(countg, rpg, bsumA, GV);
    scan_mid_kernel<<<1, 256, 0, stream>>>(bsumA, sA, NBG);
    add_gen_kernel<<<NBG, 256, 0, stream>>>(rpg, sA, GV);

    scatterg_kernel<<<(E + 255) / 256, 256, 0, stream>>>(xnode, xneis, etype, dg,
                                                         rpg, cursorg, pmeta);
    pq_kernel<<<(V / 16 + 3) / 4, 256, 0, stream>>>(feat, Wxi, P8, Qb);
    bsum_kernel<<<NB, 256, 0, stream>>>(feat, cnt_tot, Wrou, brou, Hinit,
                                        Bsum, Hb0);
    amat_kernel<<<(V + 3) / 4, 256, 0, stream>>>(pmeta, countg, rpg, rowptr,
                                                 P8, Qb, Wxi, bxi, A8, esrc);

    const ushort* Hcur = Hb0;
    ushort* bufs[2] = {HbA, HbB};
    for (int t = 0; t < 4; ++t) {
        ushort* Hn = bufs[t & 1];
        float* lg  = (t == 3) ? logits : nullptr;
        float* hf  = (t == 3) ? Hfp : nullptr;
        step_kernel<<<(V + 3) / 4, 256, 0, stream>>>(Hcur, Hn, esrc, rowptr,
                                                     A8, Bsum, W1, b1, lg, hf);
        Hcur = Hn;
    }

    reduce_max_kernel<<<256, 256, 0, stream>>>(logits, pmax);
    final_max_kernel<<<1, 256, 0, stream>>>(pmax, Mp);
    sum_kernel<<<64, 256, 0, stream>>>(Hfp, logits, Mp, spart);
    final_kernel<<<1, 64, 0, stream>>>(spart, (float*)d_out);
}

// Round 19
// 517.598 us; speedup vs baseline: 1.0237x; 1.0237x over previous
//
#include <hip/hip_runtime.h>
#include <hip/hip_bf16.h>

constexpr int V   = 100000;
constexpr int E   = 1600000;
constexpr int NET = 10;
constexpr int KXW = 138;              // W_xi row length (2*64+10)
constexpr int NB  = (V + 255) / 256;  // 391 blocks over nodes
constexpr int GN  = 8;                // partial-CSR groups (≈ XCDs)
constexpr int GV  = GN * V;           // 800000
constexpr int NBG = (GV + 255) / 256; // 3125
constexpr float MUS   = 0.1125f;      // MU / S
constexpr float SP    = 0.025f;       // int8 P scale
constexpr float LOG2E = 1.44269504f;
constexpr float S2L   = 2.0f * SP * LOG2E;   // int8 P step in exp2 domain
constexpr float AS    = MUS / 127.0f;        // int8 A decode scale

typedef __attribute__((ext_vector_type(8))) short short8;
typedef __attribute__((ext_vector_type(4))) float float4v;

__device__ __forceinline__ float fast_tanh(float x) {
    return 1.0f - 2.0f * __builtin_amdgcn_rcpf(__expf(2.0f * x) + 1.0f);
}
__device__ __forceinline__ float bflo(unsigned u) { return __uint_as_float(u << 16); }
__device__ __forceinline__ float bfhi(unsigned u) { return __uint_as_float(u & 0xffff0000u); }
__device__ __forceinline__ short f2bf(float x) {
    union { __hip_bfloat16 b; short s; } u; u.b = __float2bfloat16(x); return u.s;
}

__device__ __forceinline__ float ub0(unsigned u) {
#if __has_builtin(__builtin_amdgcn_cvt_f32_ubyte0)
    return __builtin_amdgcn_cvt_f32_ubyte0(u);
#else
    return (float)(u & 0xff);
#endif
}
__device__ __forceinline__ float ub1(unsigned u) {
#if __has_builtin(__builtin_amdgcn_cvt_f32_ubyte1)
    return __builtin_amdgcn_cvt_f32_ubyte1(u);
#else
    return (float)((u >> 8) & 0xff);
#endif
}
__device__ __forceinline__ float ub2(unsigned u) {
#if __has_builtin(__builtin_amdgcn_cvt_f32_ubyte2)
    return __builtin_amdgcn_cvt_f32_ubyte2(u);
#else
    return (float)((u >> 16) & 0xff);
#endif
}
__device__ __forceinline__ float ub3(unsigned u) {
#if __has_builtin(__builtin_amdgcn_cvt_f32_ubyte3)
    return __builtin_amdgcn_cvt_f32_ubyte3(u);
#else
    return (float)(u >> 24);
#endif
}
__device__ __forceinline__ unsigned pku8(float f, unsigned pos, unsigned old) {
#if __has_builtin(__builtin_amdgcn_cvt_pk_u8_f32)
    return __builtin_amdgcn_cvt_pk_u8_f32(f, pos, old);
#else
    return old | ((unsigned)f << (8 * pos));
#endif
}

// ---------------------------------------------------------------------------
// 8-way histogram: countg[g][v], g = blockIdx&7 (same grid as scatterg).
// ---------------------------------------------------------------------------
__global__ __launch_bounds__(256) void histg_kernel(
    const int* __restrict__ xneis, int* __restrict__ countg)
{
    int e = blockIdx.x * 256 + threadIdx.x;
    if (e >= E) return;
    int g = blockIdx.x & (GN - 1);
    int nr = xneis[e];
    if (nr < V) atomicAdd(&countg[g * V + nr], 1);
}

// Fused: cnt_tot[v] = sum_g countg[g][v]; blockwise-exclusive scan of cnt_tot.
__global__ __launch_bounds__(256) void scanV_kernel(
    const int* __restrict__ countg, int* __restrict__ cnt_tot,
    int* __restrict__ scanned, int* __restrict__ bsum)
{
    __shared__ int s[256];
    int tid = threadIdx.x;
    int i = blockIdx.x * 256 + tid;
    int c = 0;
    if (i < V) {
        #pragma unroll
        for (int g = 0; g < GN; ++g) c += countg[g * V + i];
        cnt_tot[i] = c;
    }
    s[tid] = c; __syncthreads();
    #pragma unroll
    for (int off = 1; off < 256; off <<= 1) {
        int t = (tid >= off) ? s[tid - off] : 0;
        __syncthreads();
        s[tid] += t;
        __syncthreads();
    }
    if (i < V) scanned[i] = s[tid] - c;
    if (tid == 255) bsum[blockIdx.x] = s[255];
}

// Generic block-exclusive scan (used for the GV level-0 scan).
__global__ __launch_bounds__(256) void scan_block_kernel(
    const int* __restrict__ in, int* __restrict__ out, int* __restrict__ bsum, int n)
{
    __shared__ int s[256];
    int tid = threadIdx.x;
    int i = blockIdx.x * 256 + tid;
    int v = (i < n) ? in[i] : 0;
    s[tid] = v; __syncthreads();
    #pragma unroll
    for (int off = 1; off < 256; off <<= 1) {
        int t = (tid >= off) ? s[tid - off] : 0;
        __syncthreads();
        s[tid] += t;
        __syncthreads();
    }
    if (i < n) out[i] = s[tid] - v;
    if (tid == 255) bsum[blockIdx.x] = s[255];
}

// Single-block full exclusive scan with running carry.
__global__ __launch_bounds__(256) void scan_mid_kernel(
    const int* __restrict__ in, int* __restrict__ out, int n)
{
    __shared__ int s[256];
    __shared__ int carry;
    int tid = threadIdx.x;
    if (tid == 0) carry = 0;
    __syncthreads();
    for (int base = 0; base < n; base += 256) {
        int i = base + tid;
        int x = (i < n) ? in[i] : 0;
        s[tid] = x; __syncthreads();
        #pragma unroll
        for (int off = 1; off < 256; off <<= 1) {
            int t = (tid >= off) ? s[tid - off] : 0;
            __syncthreads();
            s[tid] += t;
            __syncthreads();
        }
        int incl = s[tid];
        int c = carry;
        if (i < n) out[i] = c + incl - x;
        __syncthreads();
        if (tid == 255) carry = c + incl;
        __syncthreads();
    }
}

__global__ __launch_bounds__(256) void add_gen_kernel(
    int* __restrict__ arr, const int* __restrict__ tops, int n)
{
    int i = blockIdx.x * 256 + threadIdx.x;
    if (i < n) arr[i] += tops[i >> 8];
}

// rowptr path (V entries + total), NB <= 512
__global__ __launch_bounds__(512) void scan_tops_kernel(
    const int* __restrict__ blocksum, int* __restrict__ tops, int* __restrict__ rowptr)
{
    __shared__ int s[512];
    int tid = threadIdx.x;
    int v = (tid < NB) ? blocksum[tid] : 0;
    s[tid] = v; __syncthreads();
    #pragma unroll
    for (int off = 1; off < 512; off <<= 1) {
        int t = (tid >= off) ? s[tid - off] : 0;
        __syncthreads();
        s[tid] += t;
        __syncthreads();
    }
    if (tid < NB) tops[tid] = s[tid] - v;        // exclusive
    if (tid == 511) rowptr[V] = s[511];          // total kept edges
}

__global__ __launch_bounds__(256) void add_offsets_kernel(
    const int* __restrict__ scanned, const int* __restrict__ tops, int* __restrict__ rowptr)
{
    int i = blockIdx.x * 256 + threadIdx.x;
    if (i < V) rowptr[i] = scanned[i] + tops[blockIdx.x];
}

// Scatter into group-g partial CSR (g = blockIdx&7, same grid as histg).
// meta word: src (17 b) | et (4 b) | dg-1 (6 b)
__global__ __launch_bounds__(256) void scatterg_kernel(
    const int* __restrict__ xnode, const int* __restrict__ xneis,
    const int* __restrict__ etype, const float* __restrict__ dg,
    const int* __restrict__ rpg, int* __restrict__ cursorg,
    unsigned* __restrict__ pmeta)
{
    int e = blockIdx.x * 256 + threadIdx.x;
    if (e >= E) return;
    int g = blockIdx.x & (GN - 1);
    int nr = xneis[e];
    if (nr < V) {
        int idx = g * V + nr;
        int p = rpg[idx] + atomicAdd(&cursorg[idx], 1);
        unsigned src = (unsigned)(xnode[e] - 1);
        unsigned et  = (unsigned)(etype[e] - 1);
        unsigned dgi = (unsigned)dg[e] - 1;        // 0..63, exact
        pmeta[p] = src | (et << 17) | (dgi << 21);
    }
}

// ---------------------------------------------------------------------------
// Per-node bias sum + bf16 H_init.
// ---------------------------------------------------------------------------
__global__ __launch_bounds__(256) void bsum_kernel(
    const float* __restrict__ feat, const int* __restrict__ count,
    const float* __restrict__ Wrou, const float* __restrict__ brou,
    const float* __restrict__ Hinit, float* __restrict__ Bsum,
    ushort* __restrict__ Hb0)
{
    __shared__ float Wl[512];
    __shared__ float bl[8];
    int tid = threadIdx.x;
    for (int i = tid; i < 512; i += 256) Wl[i] = Wrou[i];
    if (tid < 8) bl[tid] = brou[tid];
    __syncthreads();

    int v = blockIdx.x * 256 + tid;
    if (v >= V) return;
    int c = count[v];
    float out[8] = {0, 0, 0, 0, 0, 0, 0, 0};
    if (c > 0) {                                  // c>0 implies v >= 1
        const float4* f4 = (const float4*)(feat + (size_t)(v - 1) * 64);
        float acc[8];
        #pragma unroll
        for (int s = 0; s < 8; ++s) acc[s] = bl[s];
        #pragma unroll 4
        for (int k = 0; k < 16; ++k) {
            float4 x = f4[k];
            #pragma unroll
            for (int s = 0; s < 8; ++s) {
                const float* w = &Wl[s * 64 + k * 4];
                acc[s] += x.x * w[0] + x.y * w[1] + x.z * w[2] + x.w * w[3];
            }
        }
        float fc = (float)c;
        #pragma unroll
        for (int s = 0; s < 8; ++s) out[s] = fc * fast_tanh(acc[s]);
    }
    float4* O = (float4*)(Bsum + (size_t)v * 8);
    O[0] = make_float4(out[0], out[1], out[2], out[3]);
    O[1] = make_float4(out[4], out[5], out[6], out[7]);

    const float* Hh = Hinit + (size_t)v * 8;
    uint4 pk;
    pk.x = (unsigned)(ushort)f2bf(Hh[0]) | ((unsigned)(ushort)f2bf(Hh[1]) << 16);
    pk.y = (unsigned)(ushort)f2bf(Hh[2]) | ((unsigned)(ushort)f2bf(Hh[3]) << 16);
    pk.z = (unsigned)(ushort)f2bf(Hh[4]) | ((unsigned)(ushort)f2bf(Hh[5]) << 16);
    pk.w = (unsigned)(ushort)f2bf(Hh[6]) | ((unsigned)(ushort)f2bf(Hh[7]) << 16);
    *(uint4*)(Hb0 + (size_t)v * 8) = pk;
}

// ---------------------------------------------------------------------------
// PQ GEMM (MFMA): P[v] -> int8 biased (6.4 MB), Q[v] -> bf16 (12.8 MB)
// ---------------------------------------------------------------------------
__global__ __launch_bounds__(256) void pq_kernel(
    const float* __restrict__ feat, const float* __restrict__ Wxi,
    unsigned char* __restrict__ P8, ushort* __restrict__ Qb)
{
    const int lane = threadIdx.x & 63, wave = threadIdx.x >> 6;
    const int quad = lane >> 4, l16 = lane & 15;

    short8 bP[4][2], bQ[4][2];
    #pragma unroll
    for (int nt = 0; nt < 4; ++nt) {
        #pragma unroll
        for (int ks = 0; ks < 2; ++ks) {
            const float* wp = Wxi + (size_t)(nt * 16 + l16) * KXW + ks * 32 + quad * 8;
            short8 p, q;
            #pragma unroll
            for (int j = 0; j < 8; ++j) { p[j] = f2bf(wp[j]); q[j] = f2bf(wp[64 + j]); }
            bP[nt][ks] = p; bQ[nt][ks] = q;
        }
    }

    int t = blockIdx.x * 4 + wave;
    if (t >= V / 16) return;
    int v0 = t * 16;

    const float* fp = feat + (size_t)(v0 + l16) * 64 + quad * 8;
    short8 a0, a1;
    #pragma unroll
    for (int j = 0; j < 8; ++j) { a0[j] = f2bf(fp[j]); a1[j] = f2bf(fp[32 + j]); }

    float4v accP[4], accQ[4];
    #pragma unroll
    for (int nt = 0; nt < 4; ++nt) {
        float4v z = {0.f, 0.f, 0.f, 0.f};
        z = __builtin_amdgcn_mfma_f32_16x16x32_bf16(a0, bP[nt][0], z, 0, 0, 0);
        z = __builtin_amdgcn_mfma_f32_16x16x32_bf16(a1, bP[nt][1], z, 0, 0, 0);
        accP[nt] = z;
        float4v w = {0.f, 0.f, 0.f, 0.f};
        w = __builtin_amdgcn_mfma_f32_16x16x32_bf16(a0, bQ[nt][0], w, 0, 0, 0);
        w = __builtin_amdgcn_mfma_f32_16x16x32_bf16(a1, bQ[nt][1], w, 0, 0, 0);
        accQ[nt] = w;
    }

    #pragma unroll
    for (int r = 0; r < 4; ++r) {
        int row = v0 + quad * 4 + r;
        #pragma unroll
        for (int nt = 0; nt < 4; ++nt) {
            int col = nt * 16 + l16;
            int q8 = (int)rintf(accP[nt][r] * (1.0f / SP)) + 128;
            q8 = min(max(q8, 0), 255);
            P8[row * 64 + col] = (unsigned char)q8;
            Qb[row * 64 + col] = (ushort)f2bf(accQ[nt][r]);
        }
    }
}

// ---------------------------------------------------------------------------
// FUSED A materialization + STEP 1. Phase 1 resolves edge metadata (one lane
// per edge); phase 2 computes the int8 A row AND accumulates step 1's dot
// with Hinit using the pre-truncation encodes qf (EXACT: a=(qf-128.5)*AS).
// Eliminates the entire step-1 kernel (one full 102 MB A8 re-read).
// ---------------------------------------------------------------------------
__global__ __launch_bounds__(256) void amat_kernel(
    const unsigned* __restrict__ pmeta, const int* __restrict__ countg,
    const int* __restrict__ rpg, const int* __restrict__ rowptr,
    const unsigned char* __restrict__ P8, const ushort* __restrict__ Qb,
    const float* __restrict__ Wxi, const float* __restrict__ bxi,
    const ushort* __restrict__ Hb0, const float* __restrict__ Bsum,
    unsigned char* __restrict__ A8, int* __restrict__ esrc,
    ushort* __restrict__ H1out)
{
    __shared__ float Wet2[NET * 64];     // 2*log2e*(Wxi[n][128+et]+bxi[n])
    __shared__ float scT[64];            // 127/dg
    int tid = threadIdx.x;
    for (int i = tid; i < NET * 64; i += 256) {
        int et = i >> 6, n = i & 63;
        Wet2[i] = 2.0f * LOG2E * (Wxi[n * KXW + 128 + et] + bxi[n]);
    }
    if (tid < 64) scT[tid] = 127.0f / (float)(tid + 1);
    __syncthreads();

    int v = blockIdx.x * 4 + (tid >> 6);
    if (v >= V) return;
    int lane = tid & 63;
    int el = lane >> 3, s = lane & 7;

    // 8-segment table (count, base) -> prefix
    int cg = 0, bg = 0;
    if (lane < 8) { cg = countg[lane * V + v]; bg = rpg[lane * V + v]; }
    int prefA[8], baseA[8];
    int pref = 0;
    #pragma unroll
    for (int g = 0; g < GN; ++g) {
        prefA[g] = pref;
        baseA[g] = __shfl(bg, g);
        pref += __shfl(cg, g);
    }
    const int deg = pref;
    const int off = rowptr[v];

    float q0, q1, q2, q3, q4, q5, q6, q7;
    {
        uint4 qu = *(const uint4*)(Qb + v * 64 + s * 8);
        const float B = 128.0f * SP, C = 2.0f * LOG2E;
        q0 = C * (bflo(qu.x) - B); q1 = C * (bfhi(qu.x) - B);
        q2 = C * (bflo(qu.y) - B); q3 = C * (bfhi(qu.y) - B);
        q4 = C * (bflo(qu.z) - B); q5 = C * (bfhi(qu.z) - B);
        q6 = C * (bflo(qu.w) - B); q7 = C * (bfhi(qu.w) - B);
    }

    float accD = 0.0f, csum = 0.0f;       // fused step-1 accumulators

    for (int base = 0; base < deg; base += 64) {
        // phase 1: this lane resolves edge (base+lane)
        unsigned m_mine = 0;
        {
            int i1 = base + lane;
            if (i1 < deg) {
                int gg = 0;
                #pragma unroll
                for (int g = 1; g < GN; ++g) if (i1 >= prefA[g]) gg = g;
                int p = baseA[gg] + (i1 - prefA[gg]);
                m_mine = pmeta[p];
                esrc[off + i1] = (int)(m_mine & 0x1FFFF);
            }
        }
        // phase 2: 8 edges per sub-round, meta via shfl broadcast
        int nb = deg - base;
        for (int k = 0; k * 8 + el < nb && k < 8; ++k) {
            int ib = k * 8 + el;
            int i = base + ib;
            unsigned m = __shfl(m_mine, ib);
            int src = (int)(m & 0x1FFFF);
            int et  = (int)((m >> 17) & 0xF);
            float kk  = scT[m >> 21];
            float m2k = -2.0f * kk;
            float ck  = kk + 128.5f;

            uint2 pu = *(const uint2*)(P8 + src * 64 + s * 8);
            const float4* w4 = (const float4*)(&Wet2[et * 64 + s * 8]);
            float4 wa = w4[0], wb = w4[1];

            float r0 = __builtin_amdgcn_rcpf(__builtin_amdgcn_exp2f(fmaf(ub0(pu.x), S2L, q0 + wa.x)) + 1.0f);
            float r1 = __builtin_amdgcn_rcpf(__builtin_amdgcn_exp2f(fmaf(ub1(pu.x), S2L, q1 + wa.y)) + 1.0f);
            float r2 = __builtin_amdgcn_rcpf(__builtin_amdgcn_exp2f(fmaf(ub2(pu.x), S2L, q2 + wa.z)) + 1.0f);
            float r3 = __builtin_amdgcn_rcpf(__builtin_amdgcn_exp2f(fmaf(ub3(pu.x), S2L, q3 + wa.w)) + 1.0f);
            float r4 = __builtin_amdgcn_rcpf(__builtin_amdgcn_exp2f(fmaf(ub0(pu.y), S2L, q4 + wb.x)) + 1.0f);
            float r5 = __builtin_amdgcn_rcpf(__builtin_amdgcn_exp2f(fmaf(ub1(pu.y), S2L, q5 + wb.y)) + 1.0f);
            float r6 = __builtin_amdgcn_rcpf(__builtin_amdgcn_exp2f(fmaf(ub2(pu.y), S2L, q6 + wb.z)) + 1.0f);
            float r7 = __builtin_amdgcn_rcpf(__builtin_amdgcn_exp2f(fmaf(ub3(pu.y), S2L, q7 + wb.w)) + 1.0f);

            float qf0 = fmaf(r0, m2k, ck), qf1 = fmaf(r1, m2k, ck);
            float qf2 = fmaf(r2, m2k, ck), qf3 = fmaf(r3, m2k, ck);
            float qf4 = fmaf(r4, m2k, ck), qf5 = fmaf(r5, m2k, ck);
            float qf6 = fmaf(r6, m2k, ck), qf7 = fmaf(r7, m2k, ck);

            uint2 o;
            o.x = pku8(qf3, 3, pku8(qf2, 2, pku8(qf1, 1, pku8(qf0, 0, 0u))));
            o.y = pku8(qf7, 3, pku8(qf6, 2, pku8(qf5, 1, pku8(qf4, 0, 0u))));
            *(uint2*)(A8 + (unsigned)(off + i) * 64u + (unsigned)(s * 8)) = o;

            // fused step 1: dot qf with Hinit[src] (bf16, L2-resident)
            uint4 hb = *(const uint4*)(Hb0 + src * 8);
            float h0 = bflo(hb.x), h1 = bfhi(hb.x), h2 = bflo(hb.y), h3 = bfhi(hb.y);
            float h4 = bflo(hb.z), h5 = bfhi(hb.z), h6 = bflo(hb.w), h7 = bfhi(hb.w);
            accD += qf0 * h0 + qf1 * h1 + qf2 * h2 + qf3 * h3
                  + qf4 * h4 + qf5 * h5 + qf6 * h6 + qf7 * h7;
            csum += ((h0 + h1) + (h2 + h3)) + ((h4 + h5) + (h6 + h7));
        }
    }
    // reduce over el lanes (lane = el*8 + s)
    accD += __shfl_xor(accD, 8);  accD += __shfl_xor(accD, 16); accD += __shfl_xor(accD, 32);
    csum += __shfl_xor(csum, 8);  csum += __shfl_xor(csum, 16); csum += __shfl_xor(csum, 32);
    float h1v = (accD - 128.5f * csum) * AS + Bsum[v * 8 + s];
    if (el == 0)
        H1out[v * 8 + s] = (ushort)f2bf(h1v);
}

// ---------------------------------------------------------------------------
// Light step, 2x-unrolled (32 edges in flight per wave), bf16 H gathers,
// csum computed in-loop. Runs 3x (step 1 fused into amat).
// ---------------------------------------------------------------------------
__global__ __launch_bounds__(256) void step_kernel(
    const ushort* __restrict__ HbIn, ushort* __restrict__ HbOut,
    const int* __restrict__ esrc, const int* __restrict__ rowptr,
    const unsigned char* __restrict__ A8, const float* __restrict__ Bsum,
    const float* __restrict__ W1, const float* __restrict__ b1,
    float* __restrict__ logitsOut, float* __restrict__ HfpOut)
{
    int v = blockIdx.x * 4 + (threadIdx.x >> 6);
    if (v >= V) return;
    int lane = threadIdx.x & 63;
    int el = lane >> 2, q = lane & 3;

    int p0 = rowptr[v], p1 = rowptr[v + 1];

    float accE = 0.0f, accO = 0.0f, csum = 0.0f;
    int p = p0 + el;
    for (; p + 16 < p1; p += 32) {
        int srcA = esrc[p], srcB = esrc[p + 16];
        uint4 auA = *(const uint4*)(A8 + (unsigned)p * 64u + (unsigned)(q * 16));
        uint4 auB = *(const uint4*)(A8 + (unsigned)(p + 16) * 64u + (unsigned)(q * 16));
        uint4 hbA = *(const uint4*)(HbIn + srcA * 8);
        uint4 hbB = *(const uint4*)(HbIn + srcB * 8);

        float a0x = bflo(hbA.x), a0y = bfhi(hbA.x), a0z = bflo(hbA.y), a0w = bfhi(hbA.y);
        float a1x = bflo(hbA.z), a1y = bfhi(hbA.z), a1z = bflo(hbA.w), a1w = bfhi(hbA.w);
        csum += ((a0x + a0y) + (a0z + a0w)) + ((a1x + a1y) + (a1z + a1w));
        accE += ub0(auA.x) * a0x + ub1(auA.x) * a0y + ub2(auA.x) * a0z + ub3(auA.x) * a0w
              + ub0(auA.y) * a1x + ub1(auA.y) * a1y + ub2(auA.y) * a1z + ub3(auA.y) * a1w;
        accO += ub0(auA.z) * a0x + ub1(auA.z) * a0y + ub2(auA.z) * a0z + ub3(auA.z) * a0w
              + ub0(auA.w) * a1x + ub1(auA.w) * a1y + ub2(auA.w) * a1z + ub3(auA.w) * a1w;

        float b0x = bflo(hbB.x), b0y = bfhi(hbB.x), b0z = bflo(hbB.y), b0w = bfhi(hbB.y);
        float b1x = bflo(hbB.z), b1y = bfhi(hbB.z), b1z = bflo(hbB.w), b1w = bfhi(hbB.w);
        csum += ((b0x + b0y) + (b0z + b0w)) + ((b1x + b1y) + (b1z + b1w));
        accE += ub0(auB.x) * b0x + ub1(auB.x) * b0y + ub2(auB.x) * b0z + ub3(auB.x) * b0w
              + ub0(auB.y) * b1x + ub1(auB.y) * b1y + ub2(auB.y) * b1z + ub3(auB.y) * b1w;
        accO += ub0(auB.z) * b0x + ub1(auB.z) * b0y + ub2(auB.z) * b0z + ub3(auB.z) * b0w
              + ub0(auB.w) * b1x + ub1(auB.w) * b1y + ub2(auB.w) * b1z + ub3(auB.w) * b1w;
    }
    if (p < p1) {
        int src = esrc[p];
        uint4 au = *(const uint4*)(A8 + (unsigned)p * 64u + (unsigned)(q * 16));
        uint4 hb = *(const uint4*)(HbIn + src * 8);
        float h0x = bflo(hb.x), h0y = bfhi(hb.x), h0z = bflo(hb.y), h0w = bfhi(hb.y);
        float h1x = bflo(hb.z), h1y = bfhi(hb.z), h1z = bflo(hb.w), h1w = bfhi(hb.w);
        csum += ((h0x + h0y) + (h0z + h0w)) + ((h1x + h1y) + (h1z + h1w));
        accE += ub0(au.x) * h0x + ub1(au.x) * h0y + ub2(au.x) * h0z + ub3(au.x) * h0w
              + ub0(au.y) * h1x + ub1(au.y) * h1y + ub2(au.y) * h1z + ub3(au.y) * h1w;
        accO += ub0(au.z) * h0x + ub1(au.z) * h0y + ub2(au.z) * h0z + ub3(au.z) * h0w
              + ub0(au.w) * h1x + ub1(au.w) * h1y + ub2(au.w) * h1z + ub3(au.w) * h1w;
    }
    accE += __shfl_xor(accE, 4);  accE += __shfl_xor(accE, 8);
    accE += __shfl_xor(accE, 16); accE += __shfl_xor(accE, 32);
    accO += __shfl_xor(accO, 4);  accO += __shfl_xor(accO, 8);
    accO += __shfl_xor(accO, 16); accO += __shfl_xor(accO, 32);
    csum += __shfl_xor(csum, 4);  csum += __shfl_xor(csum, 8);
    csum += __shfl_xor(csum, 16); csum += __shfl_xor(csum, 32);

    float hE = (accE - 128.0f * csum) * AS + Bsum[v * 8 + q * 2];
    float hO = (accO - 128.0f * csum) * AS + Bsum[v * 8 + q * 2 + 1];

    unsigned pk = (unsigned)(ushort)f2bf(hE) | ((unsigned)(ushort)f2bf(hO) << 16);
    if (el == 0) {
        *(unsigned*)(HbOut + v * 8 + q * 2) = pk;
        if (HfpOut != nullptr)
            *(float2*)(HfpOut + v * 8 + q * 2) = make_float2(hE, hO);
    }
    if (logitsOut != nullptr) {
        float t = hE * W1[q * 2] + hO * W1[q * 2 + 1];
        t += __shfl_xor(t, 1); t += __shfl_xor(t, 2);
        if (lane == 0) logitsOut[v] = t + b1[0];
    }
}

// ---------------------------------------------------------------------------
// Epilogue
// ---------------------------------------------------------------------------
__global__ __launch_bounds__(256) void reduce_max_kernel(
    const float* __restrict__ logits, float* __restrict__ partial)
{
    float m = -INFINITY;
    for (int v = blockIdx.x * 256 + threadIdx.x; v < V; v += 256 * 256)
        m = fmaxf(m, logits[v]);
    #pragma unroll
    for (int o = 32; o > 0; o >>= 1) m = fmaxf(m, __shfl_down(m, o));
    __shared__ float sm[4];
    if ((threadIdx.x & 63) == 0) sm[threadIdx.x >> 6] = m;
    __syncthreads();
    if (threadIdx.x == 0)
        partial[blockIdx.x] = fmaxf(fmaxf(sm[0], sm[1]), fmaxf(sm[2], sm[3]));
}

__global__ __launch_bounds__(256) void final_max_kernel(
    const float* __restrict__ partial, float* __restrict__ M)
{
    float m = partial[threadIdx.x];
    #pragma unroll
    for (int o = 32; o > 0; o >>= 1) m = fmaxf(m, __shfl_down(m, o));
    __shared__ float sm[4];
    if ((threadIdx.x & 63) == 0) sm[threadIdx.x >> 6] = m;
    __syncthreads();
    if (threadIdx.x == 0) *M = fmaxf(fmaxf(sm[0], sm[1]), fmaxf(sm[2], sm[3]));
}

// Stage 1: 64 blocks write per-block partials (9 floats each) — no atomics.
__global__ __launch_bounds__(256) void sum_kernel(
    const float* __restrict__ H, const float* __restrict__ logits,
    const float* __restrict__ Mp, float* __restrict__ partial)
{
    const float M = *Mp;
    float se = 0.0f;
    float sh[8] = {0, 0, 0, 0, 0, 0, 0, 0};
    for (int v = blockIdx.x * 256 + threadIdx.x; v < V; v += 64 * 256) {
        float w = __expf(logits[v] - M);
        se += w;
        const float4* H4 = (const float4*)(H + (size_t)v * 8);
        float4 h0 = H4[0], h1 = H4[1];
        sh[0] += w * h0.x; sh[1] += w * h0.y; sh[2] += w * h0.z; sh[3] += w * h0.w;
        sh[4] += w * h1.x; sh[5] += w * h1.y; sh[6] += w * h1.z; sh[7] += w * h1.w;
    }
    #pragma unroll
    for (int o = 32; o > 0; o >>= 1) {
        se += __shfl_xor(se, o);
        #pragma unroll
        for (int i = 0; i < 8; ++i) sh[i] += __shfl_xor(sh[i], o);
    }
    __shared__ float sm[4][9];
    int wv = threadIdx.x >> 6;
    if ((threadIdx.x & 63) == 0) {
        sm[wv][8] = se;
        #pragma unroll
        for (int i = 0; i < 8; ++i) sm[wv][i] = sh[i];
    }
    __syncthreads();
    if (threadIdx.x == 0) {
        #pragma unroll
        for (int i = 0; i < 9; ++i)
            partial[blockIdx.x * 12 + i] = sm[0][i] + sm[1][i] + sm[2][i] + sm[3][i];
    }
}

__global__ void final_kernel(const float* __restrict__ partial, float* __restrict__ out)
{
    int lane = threadIdx.x;               // 64 threads
    float vals[9];
    #pragma unroll
    for (int i = 0; i < 9; ++i) vals[i] = partial[lane * 12 + i];
    #pragma unroll
    for (int o = 1; o < 64; o <<= 1) {
        #pragma unroll
        for (int i = 0; i < 9; ++i) vals[i] += __shfl_xor(vals[i], o);
    }
    __shared__ float res[9];
    if (lane == 0) {
        #pragma unroll
        for (int i = 0; i < 9; ++i) res[i] = vals[i];
    }
    __syncthreads();
    if (lane < 8) out[lane] = tanhf(res[lane] / res[8]);
}

// ---------------------------------------------------------------------------
extern "C" void kernel_launch(void* const* d_in, const int* in_sizes, int n_in,
                              void* d_out, int out_size, void* d_ws, size_t ws_size,
                              hipStream_t stream)
{
    const float* feat  = (const float*)d_in[0];
    const int*   xnode = (const int*)d_in[1];
    const int*   xneis = (const int*)d_in[2];
    const int*   etype = (const int*)d_in[3];
    const float* dg    = (const float*)d_in[4];
    const float* Hinit = (const float*)d_in[5];
    const float* Wxi   = (const float*)d_in[6];
    const float* bxi   = (const float*)d_in[7];
    const float* Wrou  = (const float*)d_in[8];
    const float* brou  = (const float*)d_in[9];
    const float* W1    = (const float*)d_in[10];
    const float* b1    = (const float*)d_in[11];

    char* ws = (char*)d_ws;
    auto alloc = [&](size_t bytes) -> char* {
        char* p = ws; ws += (bytes + 255) & ~(size_t)255; return p;
    };
    // Budget: ~158 MB total (fits 256 MiB ws)
    unsigned char* A8 = (unsigned char*)alloc((size_t)E * 64); // 102.4 MB int8 A
    unsigned char* P8 = (unsigned char*)alloc((size_t)V * 64); // 6.4 MB int8 P
    ushort*   Qb      = (ushort*)alloc((size_t)V * 64 * 2);    // 12.8 MB bf16 Q
    unsigned* pmeta   = (unsigned*)alloc((size_t)E * 4);       // 6.4 MB partial CSR
    int*      esrc    = (int*)alloc((size_t)E * 4);            // 6.4 MB node-major src
    int*      countg  = (int*)alloc((size_t)2 * GV * 4);       // countg + cursorg
    int*      cursorg = countg + GV;
    int*      rpg     = (int*)alloc((size_t)GV * 4);           // 3.2 MB
    int*      cnt_tot = (int*)alloc((size_t)V * 4);
    int*      scannedT= (int*)alloc((size_t)V * 4);
    int*      rowptr  = (int*)alloc((size_t)(V + 1) * 4);
    int*      bsumT   = (int*)alloc(512 * 4);
    int*      topsT   = (int*)alloc(512 * 4);
    int*      bsumA   = (int*)alloc((size_t)NBG * 4);
    int*      sA      = (int*)alloc((size_t)NBG * 4);
    ushort*   Hb0     = (ushort*)alloc((size_t)V * 8 * 2);     // 1.6 MB bf16 H
    ushort*   HbA     = (ushort*)alloc((size_t)V * 8 * 2);
    ushort*   HbB     = (ushort*)alloc((size_t)V * 8 * 2);
    float*    Hfp     = (float*)alloc((size_t)V * 8 * 4);      // fp32 H (last step)
    float*    Bsum    = (float*)alloc((size_t)V * 8 * 4);
    float*    logits  = (float*)alloc((size_t)V * 4);
    float*    pmax    = (float*)alloc(256 * 4);
    float*    Mp      = (float*)alloc(16);
    float*    spart   = (float*)alloc(64 * 12 * 4);

    hipMemsetAsync(countg, 0, (size_t)2 * GV * 4, stream);
    histg_kernel<<<(E + 255) / 256, 256, 0, stream>>>(xneis, countg);
    scanV_kernel<<<NB, 256, 0, stream>>>(countg, cnt_tot, scannedT, bsumT);
    scan_tops_kernel<<<1, 512, 0, stream>>>(bsumT, topsT, rowptr);
    add_offsets_kernel<<<NB, 256, 0, stream>>>(scannedT, topsT, rowptr);
    scan_block_kernel<<<NBG, 256, 0, stream>>>(countg, rpg, bsumA, GV);
    scan_mid_kernel<<<1, 256, 0, stream>>>(bsumA, sA, NBG);
    add_gen_kernel<<<NBG, 256, 0, stream>>>(rpg, sA, GV);

    scatterg_kernel<<<(E + 255) / 256, 256, 0, stream>>>(xnode, xneis, etype, dg,
                                                         rpg, cursorg, pmeta);
    pq_kernel<<<(V / 16 + 3) / 4, 256, 0, stream>>>(feat, Wxi, P8, Qb);
    bsum_kernel<<<NB, 256, 0, stream>>>(feat, cnt_tot, Wrou, brou, Hinit,
                                        Bsum, Hb0);
    // amat + fused step 1: writes A8, esrc, and H1 (bf16) in one pass
    amat_kernel<<<(V + 3) / 4, 256, 0, stream>>>(pmeta, countg, rpg, rowptr,
                                                 P8, Qb, Wxi, bxi, Hb0, Bsum,
                                                 A8, esrc, HbA);

    // steps 2..4
    const ushort* Hcur = HbA;
    ushort* bufs[2] = {HbB, HbA};
    for (int t = 0; t < 3; ++t) {
        ushort* Hn = bufs[t & 1];
        float* lg  = (t == 2) ? logits : nullptr;
        float* hf  = (t == 2) ? Hfp : nullptr;
        step_kernel<<<(V + 3) / 4, 256, 0, stream>>>(Hcur, Hn, esrc, rowptr,
                                                     A8, Bsum, W1, b1, lg, hf);
        Hcur = Hn;
    }

    reduce_max_kernel<<<256, 256, 0, stream>>>(logits, pmax);
    final_max_kernel<<<1, 256, 0, stream>>>(pmax, Mp);
    sum_kernel<<<64, 256, 0, stream>>>(Hfp, logits, Mp, spart);
    final_kernel<<<1, 64, 0, stream>>>(spart, (float*)d_out);
}